// Round 7
// baseline (524.015 us; speedup 1.0000x reference)
//
#include <hip/hip_runtime.h>
#include <math.h>

#define IN_DIM 1536
#define HID 512
#define MID 128
#define OUTC 5
#define HEADS 8
#define NEG_SLOPE 0.2f
#define BN_EPS 1e-5f

typedef __attribute__((ext_vector_type(8))) short s16x8;
typedef __attribute__((ext_vector_type(4))) float fx4;

__device__ __forceinline__ unsigned short bf16_rne(float f) {
    unsigned int u = __float_as_uint(f);
    u += 0x7fffu + ((u >> 16) & 1u);
    return (unsigned short)(u >> 16);
}
__device__ __forceinline__ float bf16_to_f32(unsigned short u) {
    return __uint_as_float((unsigned int)u << 16);
}

__device__ __forceinline__ void async_copy16(void* lds, const void* g) {
    __builtin_amdgcn_global_load_lds(
        (const __attribute__((address_space(1))) unsigned int*)g,
        (__attribute__((address_space(3))) unsigned int*)lds, 16, 0, 0);
}

// truncate 8 f32 -> bf16x8 (RTZ on mantissa; bias ~2^-9, invisible vs 0.0156)
__device__ __forceinline__ s16x8 trunc8(float4 f0, float4 f1) {
    union { unsigned int u[4]; s16x8 s; } r;
    r.u[0] = (__float_as_uint(f0.x) >> 16) | (__float_as_uint(f0.y) & 0xFFFF0000u);
    r.u[1] = (__float_as_uint(f0.z) >> 16) | (__float_as_uint(f0.w) & 0xFFFF0000u);
    r.u[2] = (__float_as_uint(f1.x) >> 16) | (__float_as_uint(f1.y) & 0xFFFF0000u);
    r.u[3] = (__float_as_uint(f1.z) >> 16) | (__float_as_uint(f1.w) & 0xFFFF0000u);
    return r.s;
}

// ---------------------------------------------------------------------------
// CSR build: histogram -> single-block scan -> scatter
// ---------------------------------------------------------------------------
__global__ void hist_kernel(const int* __restrict__ ei, int* __restrict__ deg,
                            int ET, int E) {
    int e = blockIdx.x * blockDim.x + threadIdx.x;
    if (e >= ET) return;
    int dst = (e < E) ? ei[E + e] : (e - E);
    atomicAdd(&deg[dst], 1);
}

__global__ __launch_bounds__(1024) void scan_kernel(const int* __restrict__ deg,
                                                    int* __restrict__ row_ptr,
                                                    int* __restrict__ cursor, int n) {
    __shared__ int partial[1024];
    int tid = threadIdx.x;
    int per = (n + 1023) / 1024;
    int base = tid * per;
    int s = 0;
    for (int i = 0; i < per; ++i) {
        int idx = base + i;
        if (idx < n) s += deg[idx];
    }
    partial[tid] = s;
    __syncthreads();
    for (int off = 1; off < 1024; off <<= 1) {
        int v = (tid >= off) ? partial[tid - off] : 0;
        __syncthreads();
        partial[tid] += v;
        __syncthreads();
    }
    int prefix = (tid == 0) ? 0 : partial[tid - 1];
    for (int i = 0; i < per; ++i) {
        int idx = base + i;
        if (idx < n) {
            row_ptr[idx] = prefix;
            cursor[idx] = prefix;
            prefix += deg[idx];
        }
    }
    if (tid == 1023) row_ptr[n] = partial[1023];
}

__global__ void scatter_kernel(const int* __restrict__ ei, int* __restrict__ cursor,
                               int* __restrict__ csr_src, int ET, int E) {
    int e = blockIdx.x * blockDim.x + threadIdx.x;
    if (e >= ET) return;
    int src, dst;
    if (e < E) { src = ei[e]; dst = ei[E + e]; }
    else       { src = dst = e - E; }
    int slot = atomicAdd(&cursor[dst], 1);
    csr_src[slot] = src;
}

// ---------------------------------------------------------------------------
// Transpose + bf16 split of weights (RNE): W[K][N] -> Th (and Tl if WLO) [N][K]
// ---------------------------------------------------------------------------
template <bool WLO>
__global__ __launch_bounds__(256) void transpose_split(
    const float* __restrict__ W, unsigned short* __restrict__ Th,
    unsigned short* __restrict__ Tl, int K, int Nn) {
    __shared__ float tile[32][33];
    int kb = blockIdx.y * 32, nb = blockIdx.x * 32;
    int tx = threadIdx.x & 31, ty = threadIdx.x >> 5;
#pragma unroll
    for (int r = 0; r < 4; ++r)
        tile[ty + r * 8][tx] = W[(size_t)(kb + ty + r * 8) * Nn + nb + tx];
    __syncthreads();
#pragma unroll
    for (int r = 0; r < 4; ++r) {
        int n = ty + r * 8;
        float v = tile[tx][n];
        unsigned short hi = bf16_rne(v);
        size_t o = (size_t)(nb + n) * K + kb + tx;
        Th[o] = hi;
        if (WLO) {
            float hif = __uint_as_float((unsigned int)hi << 16);
            Tl[o] = bf16_rne(v - hif);
        }
    }
}

// ---------------------------------------------------------------------------
// GEMM1 (split-K x2): Cpart[ks] = A[:, ks*K/2:(ks+1)*K/2] @ W1[same rows].
// A fp32 prefetched to registers, trunc->bf16, ds_write (XOR-swizzled 64B
// rows, zero conflicts — R6 verified). B bf16 single-term via global_load_lds.
// Tile 128x128, BK=32, dbuf, one barrier/iter. Grid 1280 = 5 blocks/CU
// (the R6 limiter was grid=628 -> 2.45 blocks/CU; LDS 32KB caps at 5).
// Swizzle: 8 consecutive same-XCD ids (b%8 fixed) = all (ym,ks) of one xm.
// ---------------------------------------------------------------------------
__global__ __launch_bounds__(256) void gemm1_kernel(
    const float* __restrict__ A, const unsigned short* __restrict__ Bh,
    float* __restrict__ Cpart, int M, int N, int K, int MBLK) {
    int b = blockIdx.x;
    int xm = (b & 7) + 8 * (b >> 6);
    int sub = (b >> 3) & 7;
    int ym = sub >> 1;
    int ks = sub & 1;
    if (xm >= MBLK) return;
    const int kbase = ks * (K / 2);
    const int khalf = K / 2;

    __shared__ unsigned short Asb[2][128 * 32];   // 8 KB each
    __shared__ unsigned short Bsb[2][128 * 32];   // 8 KB each

    const int tid = threadIdx.x;
    const int lane = tid & 63;
    const int wv = tid >> 6;
    const int row0 = xm * 128;
    const int nb0 = ym * 128;
    const int col = lane & 15;
    const int quad = lane >> 4;
    const int m0 = (wv >> 1) * 64;
    const int n0 = (wv & 1) * 64;

    // A staging: thread -> (row = tid>>1, half = tid&1), 16 fp32 -> 2 bf16x8
    const int ar = tid >> 1;
    const int ahf = tid & 1;
    const int akey = (ar >> 1) & 3;
    const int as0 = (2 * ahf) ^ akey;
    const int as1 = (2 * ahf + 1) ^ akey;
    int agr = row0 + ar; if (agr >= M) agr = M - 1;
    const float* aptr = A + (size_t)agr * K + kbase + ahf * 16;

    // B staging: 1KB instr = 16 rows x 64B; fetched chunk = slot ^ ((row>>1)&3)
    const int b_row = lane >> 2;
    const int b_chunk = (lane & 3) ^ ((lane >> 3) & 3);
    const size_t bg0 = (size_t)(nb0 + (wv * 2 + 0) * 16 + b_row) * K + kbase + b_chunk * 8;
    const size_t bg1 = (size_t)(nb0 + (wv * 2 + 1) * 16 + b_row) * K + kbase + b_chunk * 8;

    const int rsw = (col >> 1) & 3;   // fragment-read swizzle key

    fx4 acc[4][4];
#pragma unroll
    for (int i = 0; i < 4; ++i)
#pragma unroll
        for (int j = 0; j < 4; ++j) acc[i][j] = (fx4){0.f, 0.f, 0.f, 0.f};

    float4 a0, a1, a2, a3;
    // prologue: stage k=0 into buf 0
    async_copy16(&Bsb[0][(wv * 2 + 0) * 512], Bh + bg0);
    async_copy16(&Bsb[0][(wv * 2 + 1) * 512], Bh + bg1);
    a0 = *(const float4*)(aptr + 0);
    a1 = *(const float4*)(aptr + 4);
    a2 = *(const float4*)(aptr + 8);
    a3 = *(const float4*)(aptr + 12);
    *(s16x8*)&Asb[0][ar * 32 + as0 * 8] = trunc8(a0, a1);
    *(s16x8*)&Asb[0][ar * 32 + as1 * 8] = trunc8(a2, a3);
    __syncthreads();

    int cur = 0;
    for (int k0 = 0; k0 < khalf; k0 += 32) {
        const int nxt = cur ^ 1;
        const bool has = (k0 + 32) < khalf;
        if (has) {
            const int kn = k0 + 32;
            async_copy16(&Bsb[nxt][(wv * 2 + 0) * 512], Bh + bg0 + kn);
            async_copy16(&Bsb[nxt][(wv * 2 + 1) * 512], Bh + bg1 + kn);
            const float* ap = aptr + kn;
            a0 = *(const float4*)(ap + 0);
            a1 = *(const float4*)(ap + 4);
            a2 = *(const float4*)(ap + 8);
            a3 = *(const float4*)(ap + 12);
        }
        s16x8 afr[4], bfr[4];
#pragma unroll
        for (int i = 0; i < 4; ++i)
            afr[i] = *(const s16x8*)&Asb[cur][(m0 + i * 16 + col) * 32 + (quad ^ rsw) * 8];
#pragma unroll
        for (int j = 0; j < 4; ++j)
            bfr[j] = *(const s16x8*)&Bsb[cur][(n0 + j * 16 + col) * 32 + (quad ^ rsw) * 8];
#pragma unroll
        for (int i = 0; i < 4; ++i)
#pragma unroll
            for (int j = 0; j < 4; ++j)
                acc[i][j] = __builtin_amdgcn_mfma_f32_16x16x32_bf16(afr[i], bfr[j], acc[i][j], 0, 0, 0);
        if (has) {
            *(s16x8*)&Asb[nxt][ar * 32 + as0 * 8] = trunc8(a0, a1);
            *(s16x8*)&Asb[nxt][ar * 32 + as1 * 8] = trunc8(a2, a3);
        }
        __syncthreads();
        cur = nxt;
    }

    float* Cout = Cpart + (size_t)ks * M * N;
    // C/D layout: col = lane&15, row = quad*4 + reg
#pragma unroll
    for (int i = 0; i < 4; ++i) {
        int gr0 = row0 + m0 + i * 16 + quad * 4;
#pragma unroll
        for (int j = 0; j < 4; ++j) {
            int gc = nb0 + n0 + j * 16 + col;
#pragma unroll
            for (int r = 0; r < 4; ++r) {
                int gr = gr0 + r;
                if (gr < M) Cout[(size_t)gr * N + gc] = acc[i][j][r];
            }
        }
    }
}

// ---------------------------------------------------------------------------
// Split-K combine: h1lin = bf16(Cpart[0] + Cpart[1]), float4 x2 per thread
// ---------------------------------------------------------------------------
__global__ void combine_kernel(const float* __restrict__ Cpart,
                               unsigned short* __restrict__ out, size_t n4,
                               size_t total) {
    size_t i = (size_t)blockIdx.x * blockDim.x + threadIdx.x;
    if (i >= n4) return;
    float4 a = ((const float4*)Cpart)[i];
    float4 b = ((const float4*)(Cpart + total))[i];
    ushort4 o;
    o.x = bf16_rne(a.x + b.x);
    o.y = bf16_rne(a.y + b.y);
    o.z = bf16_rne(a.z + b.z);
    o.w = bf16_rne(a.w + b.w);
    ((ushort4*)out)[i] = o;
}

// ---------------------------------------------------------------------------
// GEMM2: A bf16 [M][K], B 2-term hi/lo bf16 [N][K] (N=128). Tile 32x128 ->
// 625 blocks (2.4/CU). Double-buffered, one barrier/iter, same swizzles.
// ---------------------------------------------------------------------------
__global__ __launch_bounds__(256) void gemm2_kernel(
    const unsigned short* __restrict__ A, const unsigned short* __restrict__ Bh,
    const unsigned short* __restrict__ Bl, unsigned short* __restrict__ Cb,
    int M, int N, int K) {
    __shared__ unsigned short Asb[2][32 * 32];     // 2 KB each
    __shared__ unsigned short Bhb[2][128 * 32];    // 8 KB each
    __shared__ unsigned short Blb[2][128 * 32];    // 8 KB each

    const int tid = threadIdx.x;
    const int lane = tid & 63;
    const int wv = tid >> 6;
    const int row0 = blockIdx.x * 32;
    const int col = lane & 15;
    const int quad = lane >> 4;
    const int m0 = (wv >> 1) * 16;
    const int n0 = (wv & 1) * 64;
    const int b_row = lane >> 2;
    const int b_chunk = (lane & 3) ^ ((lane >> 3) & 3);
    const int rsw = (col >> 1) & 3;

    const int t0 = wv * 2, t1 = t0 + 1;
    const size_t bgo0 = (size_t)(t0 * 16 + b_row) * K + b_chunk * 8;
    const size_t bgo1 = (size_t)(t1 * 16 + b_row) * K + b_chunk * 8;
    int agr = row0 + wv * 16 + b_row; if (agr >= M) agr = M - 1;
    const size_t ago = (size_t)agr * K + b_chunk * 8;

    fx4 acc[4];
#pragma unroll
    for (int j = 0; j < 4; ++j) acc[j] = (fx4){0.f, 0.f, 0.f, 0.f};

    auto stage = [&](int buf, int k) {
        async_copy16(&Bhb[buf][t0 * 512], Bh + bgo0 + k);
        async_copy16(&Bhb[buf][t1 * 512], Bh + bgo1 + k);
        async_copy16(&Blb[buf][t0 * 512], Bl + bgo0 + k);
        async_copy16(&Blb[buf][t1 * 512], Bl + bgo1 + k);
        if (wv < 2) async_copy16(&Asb[buf][wv * 512], A + ago + k);
    };

    stage(0, 0);
    __syncthreads();

    int cur = 0;
    for (int k0 = 0; k0 < K; k0 += 32) {
        const int nxt = cur ^ 1;
        if (k0 + 32 < K) stage(nxt, k0 + 32);
        s16x8 a, bh4[4], bl4[4];
        a = *(const s16x8*)&Asb[cur][(m0 + col) * 32 + (quad ^ rsw) * 8];
#pragma unroll
        for (int j = 0; j < 4; ++j) {
            int rb = (n0 + j * 16 + col) * 32 + (quad ^ rsw) * 8;
            bh4[j] = *(const s16x8*)&Bhb[cur][rb];
            bl4[j] = *(const s16x8*)&Blb[cur][rb];
        }
#pragma unroll
        for (int j = 0; j < 4; ++j) {
            acc[j] = __builtin_amdgcn_mfma_f32_16x16x32_bf16(a, bl4[j], acc[j], 0, 0, 0);
            acc[j] = __builtin_amdgcn_mfma_f32_16x16x32_bf16(a, bh4[j], acc[j], 0, 0, 0);
        }
        __syncthreads();
        cur = nxt;
    }

    int gr0 = row0 + m0 + quad * 4;
#pragma unroll
    for (int j = 0; j < 4; ++j) {
        int gc = n0 + j * 16 + col;
#pragma unroll
        for (int r = 0; r < 4; ++r) {
            int gr = gr0 + r;
            if (gr < M) Cb[(size_t)gr * N + gc] = bf16_rne(acc[j][r]);
        }
    }
}

// ---------------------------------------------------------------------------
// Per-(node,head) alignment dots, bf16 feature input
// ---------------------------------------------------------------------------
template <int H, int C>
__global__ void alsd_kernel(const unsigned short* __restrict__ hlin,
                            const float* __restrict__ a_s,
                            const float* __restrict__ a_d, float* __restrict__ als,
                            float* __restrict__ ald, int n) {
    int t = blockIdx.x * blockDim.x + threadIdx.x;
    if (t >= n * H) return;
    int node = t / H, h = t % H;
    const unsigned short* row = hlin + (size_t)node * H * C + h * C;
    const float* asr = a_s + h * C;
    const float* adr = a_d + h * C;
    float ss = 0.f, sd = 0.f;
#pragma unroll
    for (int c0 = 0; c0 < C; c0 += 4) {
        ushort4 u = *(const ushort4*)&row[c0];
        float v0 = bf16_to_f32(u.x), v1 = bf16_to_f32(u.y);
        float v2 = bf16_to_f32(u.z), v3 = bf16_to_f32(u.w);
        ss += v0 * asr[c0] + v1 * asr[c0 + 1] + v2 * asr[c0 + 2] + v3 * asr[c0 + 3];
        sd += v0 * adr[c0] + v1 * adr[c0 + 1] + v2 * adr[c0 + 2] + v3 * adr[c0 + 3];
    }
    als[t] = ss;
    ald[t] = sd;
}

// ---------------------------------------------------------------------------
// Fused attention-softmax + aggregation + bias + ReLU + BN, bf16 gather.
// ---------------------------------------------------------------------------
template <int F, int VEC, bool SPLIT>
__global__ __launch_bounds__(128) void agg_fused_kernel(
    const unsigned short* __restrict__ hlin, const float* __restrict__ als,
    const float* __restrict__ ald, const int* __restrict__ row_ptr,
    const int* __restrict__ csr_src, const float* __restrict__ bias,
    const float* __restrict__ gamma, const float* __restrict__ beta,
    const float* __restrict__ mean, const float* __restrict__ var,
    float* __restrict__ outf, unsigned short* __restrict__ outh) {
    int dst = blockIdx.x;
    int tid = threadIdx.x;
    int f0 = tid * VEC;
    int h = tid >> 4;              // (512,VEC4,C64) and (128,VEC1,C16)
    __shared__ float exs[16][8];
    __shared__ int srcs[16];
    int s0 = row_ptr[dst], s1 = row_ptr[dst + 1];
    int cj = tid >> 3, ch = tid & 7;
    float ald_c = ald[dst * HEADS + ch];
    float acc[VEC];
#pragma unroll
    for (int v = 0; v < VEC; ++v) acc[v] = 0.f;
    float den = 0.f;

    for (int base = s0; base < s1; base += 16) {
        int take = min(16, s1 - base);
        if (cj < take) {
            int src = csr_src[base + cj];
            if (ch == 0) srcs[cj] = src;
            float e = als[src * HEADS + ch] + ald_c;
            e = (e >= 0.f) ? e : NEG_SLOPE * e;
            exs[cj][ch] = __expf(e);
        }
        __syncthreads();
        for (int jj = 0; jj < take; ++jj) {
            int src = srcs[jj];
            float a = exs[jj][h];
            den += a;
            const unsigned short* rp = &hlin[(size_t)src * F + f0];
            if (VEC == 4) {
                ushort4 u = *(const ushort4*)rp;
                acc[0] += a * bf16_to_f32(u.x);
                acc[1] += a * bf16_to_f32(u.y);
                acc[2] += a * bf16_to_f32(u.z);
                acc[3] += a * bf16_to_f32(u.w);
            } else {
                acc[0] += a * bf16_to_f32(rp[0]);
            }
        }
        __syncthreads();
    }

    float rd = 1.f / (den + 1e-16f);
    float res[VEC];
#pragma unroll
    for (int v = 0; v < VEC; ++v) {
        int f = f0 + v;
        float val = acc[v] * rd + bias[f];
        val = fmaxf(val, 0.f);
        val = (val - mean[f]) * rsqrtf(var[f] + BN_EPS) * gamma[f] + beta[f];
        res[v] = val;
    }
    if (SPLIT) {
        if (VEC == 4) {
            ushort4 o;
            o.x = bf16_rne(res[0]); o.y = bf16_rne(res[1]);
            o.z = bf16_rne(res[2]); o.w = bf16_rne(res[3]);
            *(ushort4*)&outh[(size_t)dst * F + f0] = o;
        } else {
            outh[(size_t)dst * F + f0] = bf16_rne(res[0]);
        }
    } else {
        if (VEC == 4) {
            *(float4*)&outf[(size_t)dst * F + f0] =
                make_float4(res[0], res[1], res[2], res[3]);
        } else {
            outf[(size_t)dst * F + f0] = res[0];
        }
    }
}

// ---------------------------------------------------------------------------
// Layer 3 linear fused with alignment dots (fp32 input from agg2)
// ---------------------------------------------------------------------------
__global__ void layer3_lin_kernel(const float* __restrict__ h2, const float* __restrict__ W3,
                                  const float* __restrict__ as3, const float* __restrict__ ad3,
                                  float* __restrict__ h3lin, float* __restrict__ als,
                                  float* __restrict__ ald, int n) {
    int node = blockIdx.x * blockDim.x + threadIdx.x;
    if (node >= n) return;
    const float* row = h2 + (size_t)node * MID;
    float acc[OUTC] = {0.f, 0.f, 0.f, 0.f, 0.f};
    for (int k = 0; k < MID; ++k) {
        float x = row[k];
#pragma unroll
        for (int c = 0; c < OUTC; ++c) acc[c] += x * W3[k * OUTC + c];
    }
    float ss = 0.f, sd = 0.f;
#pragma unroll
    for (int c = 0; c < OUTC; ++c) {
        h3lin[(size_t)node * OUTC + c] = acc[c];
        ss += acc[c] * as3[c];
        sd += acc[c] * ad3[c];
    }
    als[node] = ss;
    ald[node] = sd;
}

// ---------------------------------------------------------------------------
// Layer 3: fused single-pass softmax + aggregation + bias + log_softmax
// ---------------------------------------------------------------------------
__global__ void agg3_lsm_kernel(const float* __restrict__ h3lin, const float* __restrict__ als,
                                const float* __restrict__ ald, const int* __restrict__ row_ptr,
                                const int* __restrict__ csr_src, const float* __restrict__ b3,
                                float* __restrict__ out, int n) {
    int dst = blockIdx.x * blockDim.x + threadIdx.x;
    if (dst >= n) return;
    int s0 = row_ptr[dst], s1 = row_ptr[dst + 1];
    float ad = ald[dst];
    float den = 0.f;
    float acc[OUTC] = {0.f, 0.f, 0.f, 0.f, 0.f};
    for (int j = s0; j < s1; ++j) {
        int src = csr_src[j];
        float e = als[src] + ad;
        e = (e >= 0.f) ? e : NEG_SLOPE * e;
        float x = __expf(e);
        den += x;
#pragma unroll
        for (int c = 0; c < OUTC; ++c) acc[c] += x * h3lin[(size_t)src * OUTC + c];
    }
    float rd = 1.f / (den + 1e-16f);
    float m = -INFINITY;
#pragma unroll
    for (int c = 0; c < OUTC; ++c) {
        acc[c] = acc[c] * rd + b3[c];
        m = fmaxf(m, acc[c]);
    }
    float s = 0.f;
#pragma unroll
    for (int c = 0; c < OUTC; ++c) s += __expf(acc[c] - m);
    float lse = m + __logf(s);
#pragma unroll
    for (int c = 0; c < OUTC; ++c) out[(size_t)dst * OUTC + c] = acc[c] - lse;
}

// ---------------------------------------------------------------------------
extern "C" void kernel_launch(void* const* d_in, const int* in_sizes, int n_in,
                              void* d_out, int out_size, void* d_ws, size_t ws_size,
                              hipStream_t stream) {
    const float* x   = (const float*)d_in[0];
    const int*   ei  = (const int*)d_in[1];
    const float* W1  = (const float*)d_in[2];
    const float* as1 = (const float*)d_in[3];
    const float* ad1 = (const float*)d_in[4];
    const float* b1  = (const float*)d_in[5];
    const float* W2  = (const float*)d_in[6];
    const float* as2 = (const float*)d_in[7];
    const float* ad2 = (const float*)d_in[8];
    const float* b2  = (const float*)d_in[9];
    const float* W3  = (const float*)d_in[10];
    const float* as3 = (const float*)d_in[11];
    const float* ad3 = (const float*)d_in[12];
    const float* b3  = (const float*)d_in[13];
    const float* g1  = (const float*)d_in[14];
    const float* be1 = (const float*)d_in[15];
    const float* m1  = (const float*)d_in[16];
    const float* v1  = (const float*)d_in[17];
    const float* g2  = (const float*)d_in[18];
    const float* be2 = (const float*)d_in[19];
    const float* m2  = (const float*)d_in[20];
    const float* v2  = (const float*)d_in[21];

    const int N = in_sizes[0] / IN_DIM;       // 20000
    const int E = in_sizes[1] / 2;            // 320000
    const int ET = E + N;
    const int MBLK1 = (N + 127) / 128;        // 157
    const int MBLK2 = (N + 31) / 32;          // 625

    char* ws = (char*)d_ws;
    size_t off = 0;
    auto take = [&](size_t bytes) -> char* {
        char* p = ws + off;
        off += (bytes + 255) & ~(size_t)255;
        return p;
    };
    int* deg      = (int*)take((size_t)N * 4);
    int* row_ptr  = (int*)take((size_t)(N + 1) * 4);
    int* cursor   = (int*)take((size_t)N * 4);
    int* csr_src  = (int*)take((size_t)ET * 4);
    unsigned short* W1h = (unsigned short*)take((size_t)HID * IN_DIM * 2);
    unsigned short* W2h = (unsigned short*)take((size_t)MID * HID * 2);
    unsigned short* W2l = (unsigned short*)take((size_t)MID * HID * 2);
    float* Cpart  = (float*)take((size_t)2 * N * HID * 4);               // 82 MB
    unsigned short* h1lin = (unsigned short*)take((size_t)N * HID * 2);  // bf16
    unsigned short* h1h   = (unsigned short*)take((size_t)N * HID * 2);  // bf16
    unsigned short* h2lin = (unsigned short*)take((size_t)N * MID * 2);  // bf16
    float* h2post = (float*)take((size_t)N * MID * 4);
    float* h3lin  = (float*)take((size_t)N * OUTC * 4);
    float* als    = (float*)take((size_t)N * HEADS * 4);
    float* ald    = (float*)take((size_t)N * HEADS * 4);

    // ---- CSR build + weight prep ----
    hipMemsetAsync(deg, 0, (size_t)N * 4, stream);
    hist_kernel<<<(ET + 255) / 256, 256, 0, stream>>>(ei, deg, ET, E);
    scan_kernel<<<1, 1024, 0, stream>>>(deg, row_ptr, cursor, N);
    scatter_kernel<<<(ET + 255) / 256, 256, 0, stream>>>(ei, cursor, csr_src, ET, E);
    transpose_split<false><<<dim3(HID / 32, IN_DIM / 32), 256, 0, stream>>>(
        W1, W1h, nullptr, IN_DIM, HID);
    transpose_split<true><<<dim3(MID / 32, HID / 32), 256, 0, stream>>>(
        W2, W2h, W2l, HID, MID);

    // ---- Layer 1: 1536 -> 8x64, ReLU, BN ----
    gemm1_kernel<<<1280, 256, 0, stream>>>(x, W1h, Cpart, N, HID, IN_DIM, MBLK1);
    {
        size_t total = (size_t)N * HID;
        size_t n4 = total / 4;
        combine_kernel<<<(int)((n4 + 255) / 256), 256, 0, stream>>>(Cpart, h1lin, n4, total);
    }
    alsd_kernel<HEADS, 64><<<(N * HEADS + 255) / 256, 256, 0, stream>>>(h1lin, as1, ad1, als, ald, N);
    agg_fused_kernel<HID, 4, true><<<N, 128, 0, stream>>>(
        h1lin, als, ald, row_ptr, csr_src, b1, g1, be1, m1, v1, nullptr, h1h);

    // ---- Layer 2: 512 -> 8x16, ReLU, BN ----
    gemm2_kernel<<<MBLK2, 256, 0, stream>>>(h1h, W2h, W2l, h2lin, N, MID, HID);
    alsd_kernel<HEADS, 16><<<(N * HEADS + 255) / 256, 256, 0, stream>>>(h2lin, as2, ad2, als, ald, N);
    agg_fused_kernel<MID, 1, false><<<N, 128, 0, stream>>>(
        h2lin, als, ald, row_ptr, csr_src, b2, g2, be2, m2, v2, h2post, nullptr);

    // ---- Layer 3: 128 -> 1x5, log_softmax ----
    layer3_lin_kernel<<<(N + 255) / 256, 256, 0, stream>>>(
        h2post, W3, as3, ad3, h3lin, als, ald, N);
    agg3_lsm_kernel<<<(N + 255) / 256, 256, 0, stream>>>(
        h3lin, als, ald, row_ptr, csr_src, b3, (float*)d_out, N);
}

// Round 8
// 469.262 us; speedup vs baseline: 1.1167x; 1.1167x over previous
//
#include <hip/hip_runtime.h>
#include <math.h>

#define IN_DIM 1536
#define HID 512
#define MID 128
#define OUTC 5
#define HEADS 8
#define NEG_SLOPE 0.2f
#define BN_EPS 1e-5f

typedef __attribute__((ext_vector_type(8))) short s16x8;
typedef __attribute__((ext_vector_type(4))) float fx4;

__device__ __forceinline__ unsigned short bf16_rne(float f) {
    unsigned int u = __float_as_uint(f);
    u += 0x7fffu + ((u >> 16) & 1u);
    return (unsigned short)(u >> 16);
}
__device__ __forceinline__ float bf16_to_f32(unsigned short u) {
    return __uint_as_float((unsigned int)u << 16);
}

__device__ __forceinline__ void async_copy16(void* lds, const void* g) {
    __builtin_amdgcn_global_load_lds(
        (const __attribute__((address_space(1))) unsigned int*)g,
        (__attribute__((address_space(3))) unsigned int*)lds, 16, 0, 0);
}

// ---------------------------------------------------------------------------
// CSR build: histogram -> single-block scan -> scatter
// ---------------------------------------------------------------------------
__global__ void hist_kernel(const int* __restrict__ ei, int* __restrict__ deg,
                            int ET, int E) {
    int e = blockIdx.x * blockDim.x + threadIdx.x;
    if (e >= ET) return;
    int dst = (e < E) ? ei[E + e] : (e - E);
    atomicAdd(&deg[dst], 1);
}

__global__ __launch_bounds__(1024) void scan_kernel(const int* __restrict__ deg,
                                                    int* __restrict__ row_ptr,
                                                    int* __restrict__ cursor, int n) {
    __shared__ int partial[1024];
    int tid = threadIdx.x;
    int per = (n + 1023) / 1024;
    int base = tid * per;
    int s = 0;
    for (int i = 0; i < per; ++i) {
        int idx = base + i;
        if (idx < n) s += deg[idx];
    }
    partial[tid] = s;
    __syncthreads();
    for (int off = 1; off < 1024; off <<= 1) {
        int v = (tid >= off) ? partial[tid - off] : 0;
        __syncthreads();
        partial[tid] += v;
        __syncthreads();
    }
    int prefix = (tid == 0) ? 0 : partial[tid - 1];
    for (int i = 0; i < per; ++i) {
        int idx = base + i;
        if (idx < n) {
            row_ptr[idx] = prefix;
            cursor[idx] = prefix;
            prefix += deg[idx];
        }
    }
    if (tid == 1023) row_ptr[n] = partial[1023];
}

__global__ void scatter_kernel(const int* __restrict__ ei, int* __restrict__ cursor,
                               int* __restrict__ csr_src, int ET, int E) {
    int e = blockIdx.x * blockDim.x + threadIdx.x;
    if (e >= ET) return;
    int src, dst;
    if (e < E) { src = ei[e]; dst = ei[E + e]; }
    else       { src = dst = e - E; }
    int slot = atomicAdd(&cursor[dst], 1);
    csr_src[slot] = src;
}

// ---------------------------------------------------------------------------
// x fp32 -> bf16 (RNE), 4 elems/thread
// ---------------------------------------------------------------------------
__global__ void cvt_bf16_kernel(const float* __restrict__ in,
                                unsigned short* __restrict__ out, int n4) {
    int i = blockIdx.x * blockDim.x + threadIdx.x;
    if (i >= n4) return;
    float4 v = ((const float4*)in)[i];
    ushort4 o;
    o.x = bf16_rne(v.x); o.y = bf16_rne(v.y);
    o.z = bf16_rne(v.z); o.w = bf16_rne(v.w);
    ((ushort4*)out)[i] = o;
}

// ---------------------------------------------------------------------------
// Transpose + bf16 split of weights (RNE): W[K][N] -> Th (and Tl if WLO) [N][K]
// ---------------------------------------------------------------------------
template <bool WLO>
__global__ __launch_bounds__(256) void transpose_split(
    const float* __restrict__ W, unsigned short* __restrict__ Th,
    unsigned short* __restrict__ Tl, int K, int Nn) {
    __shared__ float tile[32][33];
    int kb = blockIdx.y * 32, nb = blockIdx.x * 32;
    int tx = threadIdx.x & 31, ty = threadIdx.x >> 5;
#pragma unroll
    for (int r = 0; r < 4; ++r)
        tile[ty + r * 8][tx] = W[(size_t)(kb + ty + r * 8) * Nn + nb + tx];
    __syncthreads();
#pragma unroll
    for (int r = 0; r < 4; ++r) {
        int n = ty + r * 8;
        float v = tile[tx][n];
        unsigned short hi = bf16_rne(v);
        size_t o = (size_t)(nb + n) * K + kb + tx;
        Th[o] = hi;
        if (WLO) {
            float hif = __uint_as_float((unsigned int)hi << 16);
            Tl[o] = bf16_rne(v - hif);
        }
    }
}

// ---------------------------------------------------------------------------
// GEMM1: C=A@W1, A bf16 [M][K] (pre-converted), B bf16 [N][K] single-term.
// ALL staging via global_load_lds (no VALU round-trip — the R4 structure that
// measured fastest), dbuf with ONE barrier/iter (loads for k+1 in flight
// during compute of k), source-chunk XOR => zero bank conflicts (R6-verified),
// XCD swizzle (4 n-blocks sharing A-rows on one XCD). Tile 128x128, BK=32.
// ---------------------------------------------------------------------------
__global__ __launch_bounds__(256) void gemm1_kernel(
    const unsigned short* __restrict__ A, const unsigned short* __restrict__ Bh,
    unsigned short* __restrict__ Cb, int M, int N, int K, int MBLK) {
    int b = blockIdx.x;
    int xm = (b & 7) + 8 * (b >> 5);
    int ym = (b >> 3) & 3;
    if (xm >= MBLK) return;

    __shared__ unsigned short Asb[2][128 * 32];   // 8 KB each
    __shared__ unsigned short Bsb[2][128 * 32];   // 8 KB each

    const int tid = threadIdx.x;
    const int lane = tid & 63;
    const int wv = tid >> 6;
    const int row0 = xm * 128;
    const int nb0 = ym * 128;
    const int col = lane & 15;
    const int quad = lane >> 4;
    const int m0 = (wv >> 1) * 64;
    const int n0 = (wv & 1) * 64;

    // staging: 1KB instr = 16 rows x 64B; fetched chunk = slot ^ ((row>>1)&3)
    const int s_row = lane >> 2;
    const int s_chunk = (lane & 3) ^ ((lane >> 3) & 3);
    int agr0 = row0 + (wv * 2 + 0) * 16 + s_row; if (agr0 >= M) agr0 = M - 1;
    int agr1 = row0 + (wv * 2 + 1) * 16 + s_row; if (agr1 >= M) agr1 = M - 1;
    const size_t ag0 = (size_t)agr0 * K + s_chunk * 8;
    const size_t ag1 = (size_t)agr1 * K + s_chunk * 8;
    const size_t bg0 = (size_t)(nb0 + (wv * 2 + 0) * 16 + s_row) * K + s_chunk * 8;
    const size_t bg1 = (size_t)(nb0 + (wv * 2 + 1) * 16 + s_row) * K + s_chunk * 8;

    const int rsw = (col >> 1) & 3;   // fragment-read swizzle key

    fx4 acc[4][4];
#pragma unroll
    for (int i = 0; i < 4; ++i)
#pragma unroll
        for (int j = 0; j < 4; ++j) acc[i][j] = (fx4){0.f, 0.f, 0.f, 0.f};

    // prologue: stage k=0 into buf 0
    async_copy16(&Asb[0][(wv * 2 + 0) * 512], A + ag0);
    async_copy16(&Asb[0][(wv * 2 + 1) * 512], A + ag1);
    async_copy16(&Bsb[0][(wv * 2 + 0) * 512], Bh + bg0);
    async_copy16(&Bsb[0][(wv * 2 + 1) * 512], Bh + bg1);
    __syncthreads();

    int cur = 0;
    for (int k0 = 0; k0 < K; k0 += 32) {
        const int nxt = cur ^ 1;
        if (k0 + 32 < K) {
            const int kn = k0 + 32;
            async_copy16(&Asb[nxt][(wv * 2 + 0) * 512], A + ag0 + kn);
            async_copy16(&Asb[nxt][(wv * 2 + 1) * 512], A + ag1 + kn);
            async_copy16(&Bsb[nxt][(wv * 2 + 0) * 512], Bh + bg0 + kn);
            async_copy16(&Bsb[nxt][(wv * 2 + 1) * 512], Bh + bg1 + kn);
        }
        s16x8 afr[4], bfr[4];
#pragma unroll
        for (int i = 0; i < 4; ++i)
            afr[i] = *(const s16x8*)&Asb[cur][(m0 + i * 16 + col) * 32 + (quad ^ rsw) * 8];
#pragma unroll
        for (int j = 0; j < 4; ++j)
            bfr[j] = *(const s16x8*)&Bsb[cur][(n0 + j * 16 + col) * 32 + (quad ^ rsw) * 8];
#pragma unroll
        for (int i = 0; i < 4; ++i)
#pragma unroll
            for (int j = 0; j < 4; ++j)
                acc[i][j] = __builtin_amdgcn_mfma_f32_16x16x32_bf16(afr[i], bfr[j], acc[i][j], 0, 0, 0);
        __syncthreads();   // drains vmcnt: nxt staging complete; cur safe to overwrite
        cur = nxt;
    }

    // C/D layout: col = lane&15, row = quad*4 + reg
#pragma unroll
    for (int i = 0; i < 4; ++i) {
        int gr0 = row0 + m0 + i * 16 + quad * 4;
#pragma unroll
        for (int j = 0; j < 4; ++j) {
            int gc = nb0 + n0 + j * 16 + col;
#pragma unroll
            for (int r = 0; r < 4; ++r) {
                int gr = gr0 + r;
                if (gr < M) Cb[(size_t)gr * N + gc] = bf16_rne(acc[i][j][r]);
            }
        }
    }
}

// ---------------------------------------------------------------------------
// GEMM2: A bf16 [M][K], B 2-term hi/lo bf16 [N][K] (N=128). Tile 32x128 ->
// 625 blocks. Double-buffered, one barrier/iter, same swizzles.
// ---------------------------------------------------------------------------
__global__ __launch_bounds__(256) void gemm2_kernel(
    const unsigned short* __restrict__ A, const unsigned short* __restrict__ Bh,
    const unsigned short* __restrict__ Bl, unsigned short* __restrict__ Cb,
    int M, int N, int K) {
    __shared__ unsigned short Asb[2][32 * 32];     // 2 KB each
    __shared__ unsigned short Bhb[2][128 * 32];    // 8 KB each
    __shared__ unsigned short Blb[2][128 * 32];    // 8 KB each

    const int tid = threadIdx.x;
    const int lane = tid & 63;
    const int wv = tid >> 6;
    const int row0 = blockIdx.x * 32;
    const int col = lane & 15;
    const int quad = lane >> 4;
    const int m0 = (wv >> 1) * 16;
    const int n0 = (wv & 1) * 64;
    const int b_row = lane >> 2;
    const int b_chunk = (lane & 3) ^ ((lane >> 3) & 3);
    const int rsw = (col >> 1) & 3;

    const int t0 = wv * 2, t1 = t0 + 1;
    const size_t bgo0 = (size_t)(t0 * 16 + b_row) * K + b_chunk * 8;
    const size_t bgo1 = (size_t)(t1 * 16 + b_row) * K + b_chunk * 8;
    int agr = row0 + wv * 16 + b_row; if (agr >= M) agr = M - 1;
    const size_t ago = (size_t)agr * K + b_chunk * 8;

    fx4 acc[4];
#pragma unroll
    for (int j = 0; j < 4; ++j) acc[j] = (fx4){0.f, 0.f, 0.f, 0.f};

    auto stage = [&](int buf, int k) {
        async_copy16(&Bhb[buf][t0 * 512], Bh + bgo0 + k);
        async_copy16(&Bhb[buf][t1 * 512], Bh + bgo1 + k);
        async_copy16(&Blb[buf][t0 * 512], Bl + bgo0 + k);
        async_copy16(&Blb[buf][t1 * 512], Bl + bgo1 + k);
        if (wv < 2) async_copy16(&Asb[buf][wv * 512], A + ago + k);
    };

    stage(0, 0);
    __syncthreads();

    int cur = 0;
    for (int k0 = 0; k0 < K; k0 += 32) {
        const int nxt = cur ^ 1;
        if (k0 + 32 < K) stage(nxt, k0 + 32);
        s16x8 a, bh4[4], bl4[4];
        a = *(const s16x8*)&Asb[cur][(m0 + col) * 32 + (quad ^ rsw) * 8];
#pragma unroll
        for (int j = 0; j < 4; ++j) {
            int rb = (n0 + j * 16 + col) * 32 + (quad ^ rsw) * 8;
            bh4[j] = *(const s16x8*)&Bhb[cur][rb];
            bl4[j] = *(const s16x8*)&Blb[cur][rb];
        }
#pragma unroll
        for (int j = 0; j < 4; ++j) {
            acc[j] = __builtin_amdgcn_mfma_f32_16x16x32_bf16(a, bl4[j], acc[j], 0, 0, 0);
            acc[j] = __builtin_amdgcn_mfma_f32_16x16x32_bf16(a, bh4[j], acc[j], 0, 0, 0);
        }
        __syncthreads();
        cur = nxt;
    }

    int gr0 = row0 + m0 + quad * 4;
#pragma unroll
    for (int j = 0; j < 4; ++j) {
        int gc = n0 + j * 16 + col;
#pragma unroll
        for (int r = 0; r < 4; ++r) {
            int gr = gr0 + r;
            if (gr < M) Cb[(size_t)gr * N + gc] = bf16_rne(acc[j][r]);
        }
    }
}

// ---------------------------------------------------------------------------
// Per-(node,head) alignment dots, bf16 feature input
// ---------------------------------------------------------------------------
template <int H, int C>
__global__ void alsd_kernel(const unsigned short* __restrict__ hlin,
                            const float* __restrict__ a_s,
                            const float* __restrict__ a_d, float* __restrict__ als,
                            float* __restrict__ ald, int n) {
    int t = blockIdx.x * blockDim.x + threadIdx.x;
    if (t >= n * H) return;
    int node = t / H, h = t % H;
    const unsigned short* row = hlin + (size_t)node * H * C + h * C;
    const float* asr = a_s + h * C;
    const float* adr = a_d + h * C;
    float ss = 0.f, sd = 0.f;
#pragma unroll
    for (int c0 = 0; c0 < C; c0 += 4) {
        ushort4 u = *(const ushort4*)&row[c0];
        float v0 = bf16_to_f32(u.x), v1 = bf16_to_f32(u.y);
        float v2 = bf16_to_f32(u.z), v3 = bf16_to_f32(u.w);
        ss += v0 * asr[c0] + v1 * asr[c0 + 1] + v2 * asr[c0 + 2] + v3 * asr[c0 + 3];
        sd += v0 * adr[c0] + v1 * adr[c0 + 1] + v2 * adr[c0 + 2] + v3 * adr[c0 + 3];
    }
    als[t] = ss;
    ald[t] = sd;
}

// ---------------------------------------------------------------------------
// Fused attention-softmax + aggregation + bias + ReLU + BN, bf16 gather.
// ---------------------------------------------------------------------------
template <int F, int VEC, bool SPLIT>
__global__ __launch_bounds__(128) void agg_fused_kernel(
    const unsigned short* __restrict__ hlin, const float* __restrict__ als,
    const float* __restrict__ ald, const int* __restrict__ row_ptr,
    const int* __restrict__ csr_src, const float* __restrict__ bias,
    const float* __restrict__ gamma, const float* __restrict__ beta,
    const float* __restrict__ mean, const float* __restrict__ var,
    float* __restrict__ outf, unsigned short* __restrict__ outh) {
    int dst = blockIdx.x;
    int tid = threadIdx.x;
    int f0 = tid * VEC;
    int h = tid >> 4;              // (512,VEC4,C64) and (128,VEC1,C16)
    __shared__ float exs[16][8];
    __shared__ int srcs[16];
    int s0 = row_ptr[dst], s1 = row_ptr[dst + 1];
    int cj = tid >> 3, ch = tid & 7;
    float ald_c = ald[dst * HEADS + ch];
    float acc[VEC];
#pragma unroll
    for (int v = 0; v < VEC; ++v) acc[v] = 0.f;
    float den = 0.f;

    for (int base = s0; base < s1; base += 16) {
        int take = min(16, s1 - base);
        if (cj < take) {
            int src = csr_src[base + cj];
            if (ch == 0) srcs[cj] = src;
            float e = als[src * HEADS + ch] + ald_c;
            e = (e >= 0.f) ? e : NEG_SLOPE * e;
            exs[cj][ch] = __expf(e);
        }
        __syncthreads();
        for (int jj = 0; jj < take; ++jj) {
            int src = srcs[jj];
            float a = exs[jj][h];
            den += a;
            const unsigned short* rp = &hlin[(size_t)src * F + f0];
            if (VEC == 4) {
                ushort4 u = *(const ushort4*)rp;
                acc[0] += a * bf16_to_f32(u.x);
                acc[1] += a * bf16_to_f32(u.y);
                acc[2] += a * bf16_to_f32(u.z);
                acc[3] += a * bf16_to_f32(u.w);
            } else {
                acc[0] += a * bf16_to_f32(rp[0]);
            }
        }
        __syncthreads();
    }

    float rd = 1.f / (den + 1e-16f);
    float res[VEC];
#pragma unroll
    for (int v = 0; v < VEC; ++v) {
        int f = f0 + v;
        float val = acc[v] * rd + bias[f];
        val = fmaxf(val, 0.f);
        val = (val - mean[f]) * rsqrtf(var[f] + BN_EPS) * gamma[f] + beta[f];
        res[v] = val;
    }
    if (SPLIT) {
        if (VEC == 4) {
            ushort4 o;
            o.x = bf16_rne(res[0]); o.y = bf16_rne(res[1]);
            o.z = bf16_rne(res[2]); o.w = bf16_rne(res[3]);
            *(ushort4*)&outh[(size_t)dst * F + f0] = o;
        } else {
            outh[(size_t)dst * F + f0] = bf16_rne(res[0]);
        }
    } else {
        if (VEC == 4) {
            *(float4*)&outf[(size_t)dst * F + f0] =
                make_float4(res[0], res[1], res[2], res[3]);
        } else {
            outf[(size_t)dst * F + f0] = res[0];
        }
    }
}

// ---------------------------------------------------------------------------
// Layer 3 linear fused with alignment dots (fp32 input from agg2)
// ---------------------------------------------------------------------------
__global__ void layer3_lin_kernel(const float* __restrict__ h2, const float* __restrict__ W3,
                                  const float* __restrict__ as3, const float* __restrict__ ad3,
                                  float* __restrict__ h3lin, float* __restrict__ als,
                                  float* __restrict__ ald, int n) {
    int node = blockIdx.x * blockDim.x + threadIdx.x;
    if (node >= n) return;
    const float* row = h2 + (size_t)node * MID;
    float acc[OUTC] = {0.f, 0.f, 0.f, 0.f, 0.f};
    for (int k = 0; k < MID; ++k) {
        float x = row[k];
#pragma unroll
        for (int c = 0; c < OUTC; ++c) acc[c] += x * W3[k * OUTC + c];
    }
    float ss = 0.f, sd = 0.f;
#pragma unroll
    for (int c = 0; c < OUTC; ++c) {
        h3lin[(size_t)node * OUTC + c] = acc[c];
        ss += acc[c] * as3[c];
        sd += acc[c] * ad3[c];
    }
    als[node] = ss;
    ald[node] = sd;
}

// ---------------------------------------------------------------------------
// Layer 3: fused single-pass softmax + aggregation + bias + log_softmax
// ---------------------------------------------------------------------------
__global__ void agg3_lsm_kernel(const float* __restrict__ h3lin, const float* __restrict__ als,
                                const float* __restrict__ ald, const int* __restrict__ row_ptr,
                                const int* __restrict__ csr_src, const float* __restrict__ b3,
                                float* __restrict__ out, int n) {
    int dst = blockIdx.x * blockDim.x + threadIdx.x;
    if (dst >= n) return;
    int s0 = row_ptr[dst], s1 = row_ptr[dst + 1];
    float ad = ald[dst];
    float den = 0.f;
    float acc[OUTC] = {0.f, 0.f, 0.f, 0.f, 0.f};
    for (int j = s0; j < s1; ++j) {
        int src = csr_src[j];
        float e = als[src] + ad;
        e = (e >= 0.f) ? e : NEG_SLOPE * e;
        float x = __expf(e);
        den += x;
#pragma unroll
        for (int c = 0; c < OUTC; ++c) acc[c] += x * h3lin[(size_t)src * OUTC + c];
    }
    float rd = 1.f / (den + 1e-16f);
    float m = -INFINITY;
#pragma unroll
    for (int c = 0; c < OUTC; ++c) {
        acc[c] = acc[c] * rd + b3[c];
        m = fmaxf(m, acc[c]);
    }
    float s = 0.f;
#pragma unroll
    for (int c = 0; c < OUTC; ++c) s += __expf(acc[c] - m);
    float lse = m + __logf(s);
#pragma unroll
    for (int c = 0; c < OUTC; ++c) out[(size_t)dst * OUTC + c] = acc[c] - lse;
}

// ---------------------------------------------------------------------------
extern "C" void kernel_launch(void* const* d_in, const int* in_sizes, int n_in,
                              void* d_out, int out_size, void* d_ws, size_t ws_size,
                              hipStream_t stream) {
    const float* x   = (const float*)d_in[0];
    const int*   ei  = (const int*)d_in[1];
    const float* W1  = (const float*)d_in[2];
    const float* as1 = (const float*)d_in[3];
    const float* ad1 = (const float*)d_in[4];
    const float* b1  = (const float*)d_in[5];
    const float* W2  = (const float*)d_in[6];
    const float* as2 = (const float*)d_in[7];
    const float* ad2 = (const float*)d_in[8];
    const float* b2  = (const float*)d_in[9];
    const float* W3  = (const float*)d_in[10];
    const float* as3 = (const float*)d_in[11];
    const float* ad3 = (const float*)d_in[12];
    const float* b3  = (const float*)d_in[13];
    const float* g1  = (const float*)d_in[14];
    const float* be1 = (const float*)d_in[15];
    const float* m1  = (const float*)d_in[16];
    const float* v1  = (const float*)d_in[17];
    const float* g2  = (const float*)d_in[18];
    const float* be2 = (const float*)d_in[19];
    const float* m2  = (const float*)d_in[20];
    const float* v2  = (const float*)d_in[21];

    const int N = in_sizes[0] / IN_DIM;       // 20000
    const int E = in_sizes[1] / 2;            // 320000
    const int ET = E + N;
    const int MBLK1 = (N + 127) / 128;        // 157
    const int MBLK2 = (N + 31) / 32;          // 625

    char* ws = (char*)d_ws;
    size_t off = 0;
    auto take = [&](size_t bytes) -> char* {
        char* p = ws + off;
        off += (bytes + 255) & ~(size_t)255;
        return p;
    };
    int* deg      = (int*)take((size_t)N * 4);
    int* row_ptr  = (int*)take((size_t)(N + 1) * 4);
    int* cursor   = (int*)take((size_t)N * 4);
    int* csr_src  = (int*)take((size_t)ET * 4);
    unsigned short* W1h = (unsigned short*)take((size_t)HID * IN_DIM * 2);
    unsigned short* W2h = (unsigned short*)take((size_t)MID * HID * 2);
    unsigned short* W2l = (unsigned short*)take((size_t)MID * HID * 2);
    unsigned short* xh  = (unsigned short*)take((size_t)N * IN_DIM * 2);  // 61 MB
    unsigned short* h1lin = (unsigned short*)take((size_t)N * HID * 2);   // bf16
    unsigned short* h1h   = (unsigned short*)take((size_t)N * HID * 2);   // bf16
    unsigned short* h2lin = (unsigned short*)take((size_t)N * MID * 2);   // bf16
    float* h2post = (float*)take((size_t)N * MID * 4);
    float* h3lin  = (float*)take((size_t)N * OUTC * 4);
    float* als    = (float*)take((size_t)N * HEADS * 4);
    float* ald    = (float*)take((size_t)N * HEADS * 4);

    // ---- CSR build + weight prep + x->bf16 ----
    hipMemsetAsync(deg, 0, (size_t)N * 4, stream);
    hist_kernel<<<(ET + 255) / 256, 256, 0, stream>>>(ei, deg, ET, E);
    scan_kernel<<<1, 1024, 0, stream>>>(deg, row_ptr, cursor, N);
    scatter_kernel<<<(ET + 255) / 256, 256, 0, stream>>>(ei, cursor, csr_src, ET, E);
    transpose_split<false><<<dim3(HID / 32, IN_DIM / 32), 256, 0, stream>>>(
        W1, W1h, nullptr, IN_DIM, HID);
    transpose_split<true><<<dim3(MID / 32, HID / 32), 256, 0, stream>>>(
        W2, W2h, W2l, HID, MID);
    {
        int n4 = N * IN_DIM / 4;
        cvt_bf16_kernel<<<(n4 + 255) / 256, 256, 0, stream>>>(x, xh, n4);
    }

    // ---- Layer 1: 1536 -> 8x64, ReLU, BN ----
    gemm1_kernel<<<640, 256, 0, stream>>>(xh, W1h, h1lin, N, HID, IN_DIM, MBLK1);
    alsd_kernel<HEADS, 64><<<(N * HEADS + 255) / 256, 256, 0, stream>>>(h1lin, as1, ad1, als, ald, N);
    agg_fused_kernel<HID, 4, true><<<N, 128, 0, stream>>>(
        h1lin, als, ald, row_ptr, csr_src, b1, g1, be1, m1, v1, nullptr, h1h);

    // ---- Layer 2: 512 -> 8x16, ReLU, BN ----
    gemm2_kernel<<<MBLK2, 256, 0, stream>>>(h1h, W2h, W2l, h2lin, N, MID, HID);
    alsd_kernel<HEADS, 16><<<(N * HEADS + 255) / 256, 256, 0, stream>>>(h2lin, as2, ad2, als, ald, N);
    agg_fused_kernel<MID, 1, false><<<N, 128, 0, stream>>>(
        h2lin, als, ald, row_ptr, csr_src, b2, g2, be2, m2, v2, h2post, nullptr);

    // ---- Layer 3: 128 -> 1x5, log_softmax ----
    layer3_lin_kernel<<<(N + 255) / 256, 256, 0, stream>>>(
        h2post, W3, as3, ad3, h3lin, als, ald, N);
    agg3_lsm_kernel<<<(N + 255) / 256, 256, 0, stream>>>(
        h3lin, als, ald, row_ptr, csr_src, b3, (float*)d_out, N);
}